// Round 8
// baseline (592.402 us; speedup 1.0000x reference)
//
#include <hip/hip_runtime.h>
#include <hip/hip_bf16.h>
#include <stdint.h>

typedef __bf16 bf16;
typedef short short8 __attribute__((ext_vector_type(8)));   // bf16 A/B frag (bit pattern)
typedef float f32x4 __attribute__((ext_vector_type(4)));

#define LOG2E 1.4426950408889634f

union V16 { uint4 u; short8 s; bf16 h[8]; };
union U8  { ushort4 s; bf16 h[4]; };

typedef const __attribute__((address_space(1))) void* gp_t;
typedef __attribute__((address_space(3))) void* lp_t;
__device__ __forceinline__ void gld16(const bf16* g, bf16* l) {
  __builtin_amdgcn_global_load_lds((gp_t)g, (lp_t)l, 16, 0, 0);
}

// ---- kernel Z: zero a float4 range ---------------------------------------
__global__ __launch_bounds__(256) void k_zero(float4* __restrict__ p, int n4) {
  int i = blockIdx.x * 256 + threadIdx.x;
  if (i < n4) p[i] = {0.f, 0.f, 0.f, 0.f};
}

// ---- kernel 0: f32 -> bf16 bulk convert (n multiple of 8) ---------------
__global__ __launch_bounds__(256) void k_cvt(const float* __restrict__ src,
                                             bf16* __restrict__ dst, long long n) {
  long long i = ((long long)blockIdx.x * 256 + threadIdx.x) * 8;
  if (i >= n) return;
  float4 a = *(const float4*)(src + i);
  float4 b = *(const float4*)(src + i + 4);
  U8 w0, w1;
  w0.h[0] = (bf16)a.x; w0.h[1] = (bf16)a.y; w0.h[2] = (bf16)a.z; w0.h[3] = (bf16)a.w;
  w1.h[0] = (bf16)b.x; w1.h[1] = (bf16)b.y; w1.h[2] = (bf16)b.z; w1.h[3] = (bf16)b.w;
  *(ushort4*)(dst + i)     = w0.s;
  *(ushort4*)(dst + i + 4) = w1.s;
}

// ---- kernel 1: pack adjacency rows into 512-bit masks -------------------
__global__ __launch_bounds__(256) void k_maskpack(const int* __restrict__ adj,
                                                  unsigned long long* __restrict__ mask) {
  int wid = blockIdx.x * 4 + (threadIdx.x >> 6);
  int lane = threadIdx.x & 63;
  int a = adj[(long long)wid * 64 + lane];
  unsigned long long m = __ballot(a > 0);
  if (lane == 0) mask[wid] = m;
}

// ---- kernel 2: f32 [R,C] -> bf16 [C,R] transpose+convert per z-slice ----
__global__ __launch_bounds__(256) void k_transpose(const float* __restrict__ src,
                                                   bf16* __restrict__ dst, int R, int C) {
  __shared__ float t[32][33];
  int c0 = blockIdx.x * 32, r0 = blockIdx.y * 32;
  src += (long long)blockIdx.z * R * C;
  dst += (long long)blockIdx.z * R * C;
  int tx = threadIdx.x & 31, ty = threadIdx.x >> 5;
  for (int rr = ty; rr < 32; rr += 8)
    t[rr][tx] = src[(long long)(r0 + rr) * C + (c0 + tx)];
  __syncthreads();
  for (int cc = ty; cc < 32; cc += 8)
    dst[(long long)(c0 + cc) * R + (r0 + tx)] = (bf16)t[tx][cc];
}

// ---- kernel 3: bf16 MFMA GEMM + fused f1/f2 dot epilogue ----------------
__global__ __launch_bounds__(256) void k_gemm(const bf16* __restrict__ A,
                                              const bf16* __restrict__ WT,
                                              bf16* __restrict__ outT, int K,
                                              const float* __restrict__ a1,
                                              const float* __restrict__ a2,
                                              int aStride,
                                              float* __restrict__ f1out,
                                              float* __restrict__ f2out) {
  __shared__ bf16 As[128 * 32];      // unpadded: global_load_lds lane order
  __shared__ bf16 Bs[128 * 32];
  const int nb = blockIdx.x, mb = blockIdx.y, h = blockIdx.z;
  const int tid = threadIdx.x, wave = tid >> 6, lane = tid & 63;
  const int lrow = lane & 15, quad = lane >> 4;
  const long long mbase = (long long)mb * 128;
  const int nbase = nb * 128;
  const bf16* W = WT + (long long)h * 256 * K;
  const int wm = (wave >> 1) * 64, wn = (wave & 1) * 64;
  const int srow = wave * 16 + (lane >> 2);
  const int skoff = (lane & 3) * 8;
  const bf16* ag0 = A + (mbase + srow) * K + skoff;
  const bf16* ag1 = ag0 + 64 * K;
  const bf16* bg0 = W + (long long)(nbase + srow) * K + skoff;
  const bf16* bg1 = bg0 + 64 * K;
  bf16* lA0 = As + wave * 16 * 32;
  bf16* lA1 = As + (64 + wave * 16) * 32;
  bf16* lB0 = Bs + wave * 16 * 32;
  bf16* lB1 = Bs + (64 + wave * 16) * 32;
  f32x4 acc[4][4];
#pragma unroll
  for (int i = 0; i < 4; i++)
#pragma unroll
    for (int j = 0; j < 4; j++) acc[i][j] = {0.f, 0.f, 0.f, 0.f};
  for (int k0 = 0; k0 < K; k0 += 32) {
    __syncthreads();                 // prior frag reads complete before overwrite
    gld16(ag0 + k0, lA0);
    gld16(ag1 + k0, lA1);
    gld16(bg0 + k0, lB0);
    gld16(bg1 + k0, lB1);
    __syncthreads();                 // vmcnt(0) drain: tile landed
    V16 af[4], bfx[4];
#pragma unroll
    for (int mi = 0; mi < 4; mi++)
      af[mi].u = *(const uint4*)(As + (wm + mi * 16 + lrow) * 32 + quad * 8);
#pragma unroll
    for (int ni = 0; ni < 4; ni++)
      bfx[ni].u = *(const uint4*)(Bs + (wn + ni * 16 + lrow) * 32 + quad * 8);
#pragma unroll
    for (int mi = 0; mi < 4; mi++)
#pragma unroll
      for (int ni = 0; ni < 4; ni++)
        acc[mi][ni] = __builtin_amdgcn_mfma_f32_16x16x32_bf16(af[mi].s, bfx[ni].s, acc[mi][ni], 0, 0, 0);
  }
  // D frag: col(lane&15) -> f, row(quad*4+r) -> i; write transposed
#pragma unroll
  for (int mi = 0; mi < 4; mi++) {
    long long m0 = mbase + wm + mi * 16 + quad * 4;
    int bb = (int)(m0 >> 9);
    int ir = (int)(m0 & 511);
#pragma unroll
    for (int ni = 0; ni < 4; ni++) {
      int f = nbase + wn + ni * 16 + lrow;
      U8 w;
#pragma unroll
      for (int r = 0; r < 4; r++) w.h[r] = (bf16)acc[mi][ni][r];
      *(ushort4*)(outT + (((long long)h * 32 + bb) * 256 + f) * 512 + ir) = w.s;
    }
  }
  // ---- fused f1/f2 partial dots (raw units; LOG2E applied downstream) ----
  float av1[4], av2[4];
#pragma unroll
  for (int ni = 0; ni < 4; ni++) {
    int f = nbase + wn + ni * 16 + lrow;
    av1[ni] = a1[h * aStride + f];
    av2[ni] = a2[h * aStride + f];
  }
#pragma unroll
  for (int mi = 0; mi < 4; mi++) {
#pragma unroll
    for (int r = 0; r < 4; r++) {
      float s1 = 0.f, s2 = 0.f;
#pragma unroll
      for (int ni = 0; ni < 4; ni++) {
        s1 = __builtin_fmaf(acc[mi][ni][r], av1[ni], s1);
        s2 = __builtin_fmaf(acc[mi][ni][r], av2[ni], s2);
      }
#pragma unroll
      for (int off = 1; off < 16; off <<= 1) {
        s1 += __shfl_xor(s1, off);
        s2 += __shfl_xor(s2, off);
      }
      if (lrow == 0) {
        long long m0 = mbase + wm + mi * 16 + quad * 4 + r;
        atomicAdd(&f1out[(long long)h * 16384 + m0], s1);
        atomicAdd(&f2out[(long long)h * 16384 + m0], s2);
      }
    }
  }
}

// ---- kernel 5: softmax constants c_i = M_i + log2(d_i), inputs raw ------
__global__ __launch_bounds__(256) void k_passA(const float* __restrict__ f1p,
                                               const float* __restrict__ f2p,
                                               const unsigned long long* __restrict__ mask,
                                               float* __restrict__ cc) {
  const int hb = blockIdx.x, bb = hb & 31;
  const int wave = threadIdx.x >> 6, lane = threadIdx.x & 63;
  const int i = blockIdx.y * 4 + wave;
  const float* f2 = f2p + hb * 512;
  float4 va = *(const float4*)(f2 + lane * 8);
  float4 vb = *(const float4*)(f2 + lane * 8 + 4);
  float vj[8] = {va.x, va.y, va.z, va.w, vb.x, vb.y, vb.z, vb.w};
  unsigned int mb = ((const unsigned char*)(mask + ((long long)bb * 512 + i) * 8))[lane];
  float f1 = f1p[hb * 512 + i];
  float m = -INFINITY;
#pragma unroll
  for (int t = 0; t < 8; t++)
    if ((mb >> t) & 1) m = fmaxf(m, vj[t]);
#pragma unroll
  for (int off = 32; off; off >>= 1) m = fmaxf(m, __shfl_xor(m, off));
  float s = f1 + m;
  float M2 = LOG2E * fmaxf(s, 0.2f * s);       // scaled max score (log2 units)
  float d = 0.f;
#pragma unroll
  for (int t = 0; t < 8; t++) {
    float e0 = f1 + vj[t];
    float e = fmaxf(e0, 0.2f * e0);
    float p = exp2f(__builtin_fmaf(LOG2E, e, -M2));
    d += ((mb >> t) & 1) ? p : 0.f;
  }
#pragma unroll
  for (int off = 32; off; off >>= 1) d += __shfl_xor(d, off);
  if (lane == 0) {
    float cv = M2 + log2f(d);
    if (!isfinite(M2) || !(d > 0.f)) cv = INFINITY;  // fully-masked row -> P=0
    cc[hb * 512 + i] = cv;
  }
}

// ---- kernel 6: fused masked-softmax PV, 512 threads, dbuf coop-P --------
// Block: 32 i-rows x 256 f, 8 waves = (i-half = wave>>2) x (f-quarter = wave&3).
// grid 512 = it*32 + bb (XCD swizzle). MODE0: elu+mean -> bf16. MODE1: relu -> f32.
union PvU { bf16 P[2][32 * 512]; float hs[32 * 264]; };

__device__ __forceinline__ int pchunk(int row, int c) {   // bf16 index of 8-elem chunk
  return row * 512 + (((c + 3 * row) & 63) << 3);
}

template <int NH, int MODE>
__global__ __launch_bounds__(512) void k_pv(const bf16* __restrict__ WhT,
                                            const float* __restrict__ f1p,
                                            const float* __restrict__ cc,
                                            const float* __restrict__ f2p,
                                            const unsigned long long* __restrict__ mask,
                                            void* __restrict__ outv) {
  __shared__ PvU sh;
  __shared__ unsigned char ms[32 * 64];
  const int id = blockIdx.x;
  const int bb = id & 31, it = id >> 5;
  const int ibase = it * 32;
  const int tid = threadIdx.x, wave = tid >> 6, lane = tid & 63;
  const int lrow = lane & 15, quad = lane >> 4;
  const int ih = wave >> 2, fq = wave & 3;    // wave tile: i-half, f-quarter
  const int pi = tid >> 4;           // P row 0..31 (16 threads per row)
  const int pj = tid & 15;           // column-block owner within the row
  {
    const uint4* msrc = (const uint4*)(mask + ((long long)bb * 512 + ibase) * 8);
    if (tid < 128) ((uint4*)ms)[tid] = msrc[tid];
  }
  __syncthreads();
  unsigned int mreg = 0;
#pragma unroll
  for (int t = 0; t < 4; t++)
    mreg |= (unsigned int)ms[pi * 64 + pj + t * 16] << (t * 8);
  const int fcol = fq * 64 + lrow;
  f32x4 hacc[4];
#pragma unroll
  for (int j = 0; j < 4; j++) hacc[j] = {0.f, 0.f, 0.f, 0.f};

  auto buildP = [&](int h, bf16* buf) {
    const int hb = h * 32 + bb;
    const float f1v = f1p[hb * 512 + ibase + pi];
    const float cv  = cc[hb * 512 + ibase + pi];
    const float Ac = __builtin_fmaf(LOG2E, f1v, -cv);
    const float Bc = __builtin_fmaf(0.2f * LOG2E, f1v, -cv);
    const float* f2 = f2p + hb * 512;
#pragma unroll
    for (int t = 0; t < 4; t++) {
      const int c = pj + t * 16;
      const int j0 = c * 8;
      float4 u0 = *(const float4*)(f2 + j0);
      float4 u1 = *(const float4*)(f2 + j0 + 4);
      float fj[8] = {u0.x, u0.y, u0.z, u0.w, u1.x, u1.y, u1.z, u1.w};
      unsigned int mb = (mreg >> (t * 8)) & 0xff;
      V16 pk;
#pragma unroll
      for (int u = 0; u < 8; u++) {
        float e = fmaxf(__builtin_fmaf(LOG2E, fj[u], Ac),
                        __builtin_fmaf(0.2f * LOG2E, fj[u], Bc));
        float p = ((mb >> u) & 1) ? exp2f(e) : 0.f;
        pk.h[u] = (bf16)p;
      }
      *(uint4*)(buf + pchunk(pi, c)) = pk.u;
    }
  };

  buildP(0, sh.P[0]);

  for (int h = 0; h < NH; h++) {
    const int hb = h * 32 + bb;
    __syncthreads();                  // P[h] complete; MFMA[h-1] done by all
    if (h + 1 < NH) buildP(h + 1, sh.P[(h + 1) & 1]);
    const bf16* Pb = sh.P[h & 1];
    const bf16* wt = WhT + (long long)hb * 256 * 512;
    f32x4 acc[4];
#pragma unroll
    for (int j = 0; j < 4; j++) acc[j] = {0.f, 0.f, 0.f, 0.f};
#pragma unroll 4
    for (int js = 0; js < 16; js++) {
      V16 a0, bfr[4];
      a0.u = *(const uint4*)(Pb + pchunk(ih * 16 + lrow, js * 4 + quad));
#pragma unroll
      for (int ni = 0; ni < 4; ni++)
        bfr[ni].u = *(const uint4*)(wt + (long long)(fcol + ni * 16) * 512 + js * 32 + quad * 8);
#pragma unroll
      for (int ni = 0; ni < 4; ni++)
        acc[ni] = __builtin_amdgcn_mfma_f32_16x16x32_bf16(a0.s, bfr[ni].s, acc[ni], 0, 0, 0);
    }
#pragma unroll
    for (int ni = 0; ni < 4; ni++)
#pragma unroll
      for (int r = 0; r < 4; r++) {
        float v = acc[ni][r];
        hacc[ni][r] += (MODE == 1) ? v
                     : (v > 0.f ? v : (exp2f(v * LOG2E) - 1.f));
      }
  }
  __syncthreads();                   // all MFMA reads done; hs aliases P
#pragma unroll
  for (int ni = 0; ni < 4; ni++) {
    int f = fq * 64 + ni * 16 + lrow;
#pragma unroll
    for (int r = 0; r < 4; r++) {
      int row = ih * 16 + quad * 4 + r;
      sh.hs[row * 264 + f] = hacc[ni][r];
    }
  }
  __syncthreads();
  const int row = tid >> 4, fb = (tid & 15) * 16;
  if (MODE == 1) {
    float* op = (float*)outv + (((long long)bb * 512) + ibase + row) * 256 + fb;
    for (int c0 = 0; c0 < 16; c0 += 4) {
      float4 w;
      w.x = fmaxf(sh.hs[row * 264 + fb + c0 + 0], 0.f);
      w.y = fmaxf(sh.hs[row * 264 + fb + c0 + 1], 0.f);
      w.z = fmaxf(sh.hs[row * 264 + fb + c0 + 2], 0.f);
      w.w = fmaxf(sh.hs[row * 264 + fb + c0 + 3], 0.f);
      *(float4*)(op + c0) = w;
    }
  } else {
    bf16* op = (bf16*)outv + (((long long)bb * 512) + ibase + row) * 256 + fb;
    for (int c0 = 0; c0 < 16; c0 += 4) {
      U8 w;
#pragma unroll
      for (int r = 0; r < 4; r++)
        w.h[r] = (bf16)(sh.hs[row * 264 + fb + c0 + r] * 0.125f);
      *(ushort4*)(op + c0) = w.s;
    }
  }
}

extern "C" void kernel_launch(void* const* d_in, const int* in_sizes, int n_in,
                              void* d_out, int out_size, void* d_ws, size_t ws_size,
                              hipStream_t stream) {
  const float* x    = (const float*)d_in[0];
  const int*   adj  = (const int*)d_in[1];
  const float* W0   = (const float*)d_in[2];
  const float* a1_0 = (const float*)d_in[3];
  const float* a2_0 = (const float*)d_in[4];
  const float* Wo   = (const float*)d_in[5];
  const float* a1_o = (const float*)d_in[6];
  const float* a2_o = (const float*)d_in[7];

  char* p = (char*)d_ws;
  auto take = [&](size_t n) { char* r = p; p += (n + 255) & ~(size_t)255; return r; };
  unsigned long long* maskb = (unsigned long long*)take(32ull * 512 * 8 * 8);
  bf16*  xb   = (bf16*)take(32ull * 512 * 768 * 2);
  bf16*  W0T  = (bf16*)take(8ull * 256 * 768 * 2);
  bf16*  WoT  = (bf16*)take(256ull * 256 * 2);
  bf16*  WhT  = (bf16*)take(8ull * 32 * 256 * 512 * 2);
  float* f1p1 = (float*)take(8ull * 32 * 512 * 4);   // contiguous zero-range start
  float* f2p1 = (float*)take(8ull * 32 * 512 * 4);
  float* f1p2 = (float*)take(32ull * 512 * 4);
  float* f2p2 = (float*)take(32ull * 512 * 4);       // contiguous zero-range end
  float* c1   = (float*)take(8ull * 32 * 512 * 4);
  float* c2   = (float*)take(32ull * 512 * 4);
  bf16* hmid = xb;    // xb dead after layer-1 GEMM; reuse for h_mid
  bf16* Wh2T = WhT;   // WhT dead after pv1; reuse for layer-2

  // zero f1p1..f2p2 (2*524288 + 2*65536 bytes = 73728 float4)
  k_zero<<<288, 256, 0, stream>>>((float4*)f1p1, 73728);
  k_cvt<<<6144, 256, 0, stream>>>(x, xb, 32ll * 512 * 768);
  k_maskpack<<<32768, 256, 0, stream>>>(adj, maskb);
  k_transpose<<<dim3(8, 24, 8), 256, 0, stream>>>(W0, W0T, 768, 256);
  k_transpose<<<dim3(8, 8, 1), 256, 0, stream>>>(Wo, WoT, 256, 256);
  // layer 1
  k_gemm<<<dim3(2, 128, 8), 256, 0, stream>>>(xb, W0T, WhT, 768,
                                              a1_0, a2_0, 256, f1p1, f2p1);
  k_passA<<<dim3(256, 128), 256, 0, stream>>>(f1p1, f2p1, maskb, c1);
  k_pv<8, 0><<<512, 512, 0, stream>>>(WhT, f1p1, c1, f2p1, maskb, hmid);
  // layer 2
  k_gemm<<<dim3(2, 128, 1), 256, 0, stream>>>(hmid, WoT, Wh2T, 256,
                                              a1_o, a2_o, 0, f1p2, f2p2);
  k_passA<<<dim3(32, 128), 256, 0, stream>>>(f1p2, f2p2, maskb, c2);
  k_pv<1, 1><<<512, 512, 0, stream>>>(Wh2T, f1p2, c2, f2p2, maskb, d_out);
}

// Round 9
// 449.259 us; speedup vs baseline: 1.3186x; 1.3186x over previous
//
#include <hip/hip_runtime.h>
#include <hip/hip_bf16.h>
#include <stdint.h>

typedef __bf16 bf16;
typedef short short8 __attribute__((ext_vector_type(8)));   // bf16 A/B frag (bit pattern)
typedef float f32x4 __attribute__((ext_vector_type(4)));

#define LOG2E 1.4426950408889634f

union V16 { uint4 u; short8 s; bf16 h[8]; };
union U8  { ushort4 s; bf16 h[4]; };

typedef const __attribute__((address_space(1))) void* gp_t;
typedef __attribute__((address_space(3))) void* lp_t;
__device__ __forceinline__ void gld16(const bf16* g, bf16* l) {
  __builtin_amdgcn_global_load_lds((gp_t)g, (lp_t)l, 16, 0, 0);
}

// ---- kernel Z: zero a float4 range ---------------------------------------
__global__ __launch_bounds__(256) void k_zero(float4* __restrict__ p, int n4) {
  int i = blockIdx.x * 256 + threadIdx.x;
  if (i < n4) p[i] = {0.f, 0.f, 0.f, 0.f};
}

// ---- kernel 0: f32 -> bf16 bulk convert (n multiple of 8) ---------------
__global__ __launch_bounds__(256) void k_cvt(const float* __restrict__ src,
                                             bf16* __restrict__ dst, long long n) {
  long long i = ((long long)blockIdx.x * 256 + threadIdx.x) * 8;
  if (i >= n) return;
  float4 a = *(const float4*)(src + i);
  float4 b = *(const float4*)(src + i + 4);
  U8 w0, w1;
  w0.h[0] = (bf16)a.x; w0.h[1] = (bf16)a.y; w0.h[2] = (bf16)a.z; w0.h[3] = (bf16)a.w;
  w1.h[0] = (bf16)b.x; w1.h[1] = (bf16)b.y; w1.h[2] = (bf16)b.z; w1.h[3] = (bf16)b.w;
  *(ushort4*)(dst + i)     = w0.s;
  *(ushort4*)(dst + i + 4) = w1.s;
}

// ---- kernel 1: pack adjacency rows into 512-bit masks -------------------
__global__ __launch_bounds__(256) void k_maskpack(const int* __restrict__ adj,
                                                  unsigned long long* __restrict__ mask) {
  int wid = blockIdx.x * 4 + (threadIdx.x >> 6);
  int lane = threadIdx.x & 63;
  int a = adj[(long long)wid * 64 + lane];
  unsigned long long m = __ballot(a > 0);
  if (lane == 0) mask[wid] = m;
}

// ---- kernel 2: f32 [R,C] -> bf16 [C,R] transpose+convert per z-slice ----
__global__ __launch_bounds__(256) void k_transpose(const float* __restrict__ src,
                                                   bf16* __restrict__ dst, int R, int C) {
  __shared__ float t[32][33];
  int c0 = blockIdx.x * 32, r0 = blockIdx.y * 32;
  src += (long long)blockIdx.z * R * C;
  dst += (long long)blockIdx.z * R * C;
  int tx = threadIdx.x & 31, ty = threadIdx.x >> 5;
  for (int rr = ty; rr < 32; rr += 8)
    t[rr][tx] = src[(long long)(r0 + rr) * C + (c0 + tx)];
  __syncthreads();
  for (int cc = ty; cc < 32; cc += 8)
    dst[(long long)(c0 + cc) * R + (r0 + tx)] = (bf16)t[tx][cc];
}

// ---- kernel 3: bf16 MFMA GEMM + fused f1/f2 dot epilogue ----------------
__global__ __launch_bounds__(256) void k_gemm(const bf16* __restrict__ A,
                                              const bf16* __restrict__ WT,
                                              bf16* __restrict__ outT, int K,
                                              const float* __restrict__ a1,
                                              const float* __restrict__ a2,
                                              int aStride,
                                              float* __restrict__ f1out,
                                              float* __restrict__ f2out) {
  __shared__ bf16 As[128 * 32];      // unpadded: global_load_lds lane order
  __shared__ bf16 Bs[128 * 32];
  const int nb = blockIdx.x, mb = blockIdx.y, h = blockIdx.z;
  const int tid = threadIdx.x, wave = tid >> 6, lane = tid & 63;
  const int lrow = lane & 15, quad = lane >> 4;
  const long long mbase = (long long)mb * 128;
  const int nbase = nb * 128;
  const bf16* W = WT + (long long)h * 256 * K;
  const int wm = (wave >> 1) * 64, wn = (wave & 1) * 64;
  const int srow = wave * 16 + (lane >> 2);
  const int skoff = (lane & 3) * 8;
  const bf16* ag0 = A + (mbase + srow) * K + skoff;
  const bf16* ag1 = ag0 + 64 * K;
  const bf16* bg0 = W + (long long)(nbase + srow) * K + skoff;
  const bf16* bg1 = bg0 + 64 * K;
  bf16* lA0 = As + wave * 16 * 32;
  bf16* lA1 = As + (64 + wave * 16) * 32;
  bf16* lB0 = Bs + wave * 16 * 32;
  bf16* lB1 = Bs + (64 + wave * 16) * 32;
  f32x4 acc[4][4];
#pragma unroll
  for (int i = 0; i < 4; i++)
#pragma unroll
    for (int j = 0; j < 4; j++) acc[i][j] = {0.f, 0.f, 0.f, 0.f};
  for (int k0 = 0; k0 < K; k0 += 32) {
    __syncthreads();                 // prior frag reads complete before overwrite
    gld16(ag0 + k0, lA0);
    gld16(ag1 + k0, lA1);
    gld16(bg0 + k0, lB0);
    gld16(bg1 + k0, lB1);
    __syncthreads();                 // vmcnt(0) drain: tile landed
    V16 af[4], bfx[4];
#pragma unroll
    for (int mi = 0; mi < 4; mi++)
      af[mi].u = *(const uint4*)(As + (wm + mi * 16 + lrow) * 32 + quad * 8);
#pragma unroll
    for (int ni = 0; ni < 4; ni++)
      bfx[ni].u = *(const uint4*)(Bs + (wn + ni * 16 + lrow) * 32 + quad * 8);
#pragma unroll
    for (int mi = 0; mi < 4; mi++)
#pragma unroll
      for (int ni = 0; ni < 4; ni++)
        acc[mi][ni] = __builtin_amdgcn_mfma_f32_16x16x32_bf16(af[mi].s, bfx[ni].s, acc[mi][ni], 0, 0, 0);
  }
  // D frag: col(lane&15) -> f, row(quad*4+r) -> i; write transposed
#pragma unroll
  for (int mi = 0; mi < 4; mi++) {
    long long m0 = mbase + wm + mi * 16 + quad * 4;
    int bb = (int)(m0 >> 9);
    int ir = (int)(m0 & 511);
#pragma unroll
    for (int ni = 0; ni < 4; ni++) {
      int f = nbase + wn + ni * 16 + lrow;
      U8 w;
#pragma unroll
      for (int r = 0; r < 4; r++) w.h[r] = (bf16)acc[mi][ni][r];
      *(ushort4*)(outT + (((long long)h * 32 + bb) * 256 + f) * 512 + ir) = w.s;
    }
  }
  // ---- fused f1/f2 partial dots (raw units; LOG2E applied downstream) ----
  float av1[4], av2[4];
#pragma unroll
  for (int ni = 0; ni < 4; ni++) {
    int f = nbase + wn + ni * 16 + lrow;
    av1[ni] = a1[h * aStride + f];
    av2[ni] = a2[h * aStride + f];
  }
#pragma unroll
  for (int mi = 0; mi < 4; mi++) {
#pragma unroll
    for (int r = 0; r < 4; r++) {
      float s1 = 0.f, s2 = 0.f;
#pragma unroll
      for (int ni = 0; ni < 4; ni++) {
        s1 = __builtin_fmaf(acc[mi][ni][r], av1[ni], s1);
        s2 = __builtin_fmaf(acc[mi][ni][r], av2[ni], s2);
      }
#pragma unroll
      for (int off = 1; off < 16; off <<= 1) {
        s1 += __shfl_xor(s1, off);
        s2 += __shfl_xor(s2, off);
      }
      if (lrow == 0) {
        long long m0 = mbase + wm + mi * 16 + quad * 4 + r;
        atomicAdd(&f1out[(long long)h * 16384 + m0], s1);
        atomicAdd(&f2out[(long long)h * 16384 + m0], s2);
      }
    }
  }
}

// ---- kernel 5: softmax constants c_i = M_i + log2(d_i), inputs raw ------
__global__ __launch_bounds__(256) void k_passA(const float* __restrict__ f1p,
                                               const float* __restrict__ f2p,
                                               const unsigned long long* __restrict__ mask,
                                               float* __restrict__ cc) {
  const int hb = blockIdx.x, bb = hb & 31;
  const int wave = threadIdx.x >> 6, lane = threadIdx.x & 63;
  const int i = blockIdx.y * 4 + wave;
  const float* f2 = f2p + hb * 512;
  float4 va = *(const float4*)(f2 + lane * 8);
  float4 vb = *(const float4*)(f2 + lane * 8 + 4);
  float vj[8] = {va.x, va.y, va.z, va.w, vb.x, vb.y, vb.z, vb.w};
  unsigned int mb = ((const unsigned char*)(mask + ((long long)bb * 512 + i) * 8))[lane];
  float f1 = f1p[hb * 512 + i];
  float m = -INFINITY;
#pragma unroll
  for (int t = 0; t < 8; t++)
    if ((mb >> t) & 1) m = fmaxf(m, vj[t]);
#pragma unroll
  for (int off = 32; off; off >>= 1) m = fmaxf(m, __shfl_xor(m, off));
  float s = f1 + m;
  float M2 = LOG2E * fmaxf(s, 0.2f * s);       // scaled max score (log2 units)
  float d = 0.f;
#pragma unroll
  for (int t = 0; t < 8; t++) {
    float e0 = f1 + vj[t];
    float e = fmaxf(e0, 0.2f * e0);
    float p = exp2f(__builtin_fmaf(LOG2E, e, -M2));
    d += ((mb >> t) & 1) ? p : 0.f;
  }
#pragma unroll
  for (int off = 32; off; off >>= 1) d += __shfl_xor(d, off);
  if (lane == 0) {
    float cv = M2 + log2f(d);
    if (!isfinite(M2) || !(d > 0.f)) cv = INFINITY;  // fully-masked row -> P=0
    cc[hb * 512 + i] = cv;
  }
}

// ---- kernel 6: fused masked-softmax PV: coop-P + async LDS B-staging ----
// 256 threads, grid 512 = it*32 + bb (XCD swizzle).
// Per head: build P (32x512) in LDS once; js-loop stages B 32-j chunks
// (16 KB) via global_load_lds, double-buffered; MFMA reads both from LDS.
// MODE0: elu+mean -> bf16. MODE1: relu -> f32.
union PvU { bf16 P[32 * 512]; float hs[32 * 264]; };

__device__ __forceinline__ int pchunk(int row, int c) {   // bf16 index of 8-elem chunk
  return row * 512 + (((c + 3 * row) & 63) << 3);
}

template <int NH, int MODE>
__global__ __launch_bounds__(256) void k_pv(const bf16* __restrict__ WhT,
                                            const float* __restrict__ f1p,
                                            const float* __restrict__ cc,
                                            const float* __restrict__ f2p,
                                            const unsigned long long* __restrict__ mask,
                                            void* __restrict__ outv) {
  __shared__ PvU sh;
  __shared__ bf16 Bsm[2][256 * 32];   // [buf][f][32 j] quad-rotated
  __shared__ unsigned char ms[32 * 64];
  const int id = blockIdx.x;
  const int bb = id & 31, it = id >> 5;
  const int ibase = it * 32;
  const int tid = threadIdx.x, wave = tid >> 6, lane = tid & 63;
  const int lrow = lane & 15, quad = lane >> 4;
  const int pi = tid >> 3;           // P row 0..31 (8 threads per row)
  const int pj = tid & 7;            // column-block owner within the row
  {
    const uint4* msrc = (const uint4*)(mask + ((long long)bb * 512 + ibase) * 8);
    if (tid < 128) ((uint4*)ms)[tid] = msrc[tid];
  }
  __syncthreads();
  unsigned long long mreg = 0;
#pragma unroll
  for (int t = 0; t < 8; t++)
    mreg |= (unsigned long long)ms[pi * 64 + pj + t * 8] << (t * 8);
  const int fcol = wave * 64 + lrow;
  const int pp = (quad + lrow) & 3;            // physical j-group after rotation
  const int sfo = lane >> 2;                   // staging: f offset within 16-row group
  const int sq  = ((lane & 3) - sfo) & 3;      // staging: logical j-group for phys slot
  f32x4 hacc[2][4];
#pragma unroll
  for (int i = 0; i < 2; i++)
#pragma unroll
    for (int j = 0; j < 4; j++) hacc[i][j] = {0.f, 0.f, 0.f, 0.f};

  auto buildP = [&](int h) {
    const int hb = h * 32 + bb;
    const float f1v = f1p[hb * 512 + ibase + pi];
    const float cv  = cc[hb * 512 + ibase + pi];
    const float Ac = __builtin_fmaf(LOG2E, f1v, -cv);
    const float Bc = __builtin_fmaf(0.2f * LOG2E, f1v, -cv);
    const float* f2 = f2p + hb * 512;
#pragma unroll
    for (int t = 0; t < 8; t++) {
      const int j0 = pj * 8 + t * 64;
      float4 u0 = *(const float4*)(f2 + j0);
      float4 u1 = *(const float4*)(f2 + j0 + 4);
      float fj[8] = {u0.x, u0.y, u0.z, u0.w, u1.x, u1.y, u1.z, u1.w};
      unsigned int mb = (unsigned int)(mreg >> (t * 8)) & 0xff;
      V16 pk;
#pragma unroll
      for (int u = 0; u < 8; u++) {
        float e = fmaxf(__builtin_fmaf(LOG2E, fj[u], Ac),
                        __builtin_fmaf(0.2f * LOG2E, fj[u], Bc));
        float p = ((mb >> u) & 1) ? exp2f(e) : 0.f;
        pk.h[u] = (bf16)p;
      }
      *(uint4*)(sh.P + pchunk(pi, pj + t * 8)) = pk.u;
    }
  };

  auto stageB = [&](const bf16* wt, int js, int buf) {
    const bf16* g0 = wt + js * 32 + sq * 8 + (long long)(wave * 16 + sfo) * 512;
#pragma unroll
    for (int g = 0; g < 4; g++)
      gld16(g0 + (long long)g * 64 * 512, Bsm[buf] + (g * 64 + wave * 16) * 32);
  };

  for (int h = 0; h < NH; h++) {
    const int hb = h * 32 + bb;
    const bf16* wt = WhT + (long long)hb * 256 * 512;
    __syncthreads();                  // prior head's P & Bs reads complete
    buildP(h);
    stageB(wt, 0, 0);
    __syncthreads();                  // P + Bs[0] landed (vmcnt drain)
    f32x4 acc[2][4];
#pragma unroll
    for (int i = 0; i < 2; i++)
#pragma unroll
      for (int j = 0; j < 4; j++) acc[i][j] = {0.f, 0.f, 0.f, 0.f};
    for (int js = 0; js < 16; js++) {
      if (js < 15) stageB(wt, js + 1, (js + 1) & 1);
      const bf16* Bb = Bsm[js & 1];
      V16 a0, a1v, bfr[4];
      a0.u  = *(const uint4*)(sh.P + pchunk(lrow,      js * 4 + quad));
      a1v.u = *(const uint4*)(sh.P + pchunk(16 + lrow, js * 4 + quad));
#pragma unroll
      for (int ni = 0; ni < 4; ni++)
        bfr[ni].u = *(const uint4*)(Bb + (fcol + ni * 16) * 32 + pp * 8);
#pragma unroll
      for (int ni = 0; ni < 4; ni++) {
        acc[0][ni] = __builtin_amdgcn_mfma_f32_16x16x32_bf16(a0.s,  bfr[ni].s, acc[0][ni], 0, 0, 0);
        acc[1][ni] = __builtin_amdgcn_mfma_f32_16x16x32_bf16(a1v.s, bfr[ni].s, acc[1][ni], 0, 0, 0);
      }
      __syncthreads();                // all reads of Bb done; next stage safe
    }
#pragma unroll
    for (int mi = 0; mi < 2; mi++)
#pragma unroll
      for (int ni = 0; ni < 4; ni++)
#pragma unroll
        for (int r = 0; r < 4; r++) {
          float v = acc[mi][ni][r];
          hacc[mi][ni][r] += (MODE == 1) ? v
                           : (v > 0.f ? v : (exp2f(v * LOG2E) - 1.f));
        }
  }
  __syncthreads();                   // all MFMA reads done; hs aliases P
#pragma unroll
  for (int mi = 0; mi < 2; mi++)
#pragma unroll
    for (int ni = 0; ni < 4; ni++) {
      int f = wave * 64 + ni * 16 + lrow;
#pragma unroll
      for (int r = 0; r < 4; r++) {
        int row = mi * 16 + quad * 4 + r;
        sh.hs[row * 264 + f] = hacc[mi][ni][r];
      }
    }
  __syncthreads();
  const int fb = pj * 32;
  if (MODE == 1) {
    float* op = (float*)outv + (((long long)bb * 512) + ibase + pi) * 256 + fb;
    for (int c0 = 0; c0 < 32; c0 += 4) {
      float4 w;
      w.x = fmaxf(sh.hs[pi * 264 + fb + c0 + 0], 0.f);
      w.y = fmaxf(sh.hs[pi * 264 + fb + c0 + 1], 0.f);
      w.z = fmaxf(sh.hs[pi * 264 + fb + c0 + 2], 0.f);
      w.w = fmaxf(sh.hs[pi * 264 + fb + c0 + 3], 0.f);
      *(float4*)(op + c0) = w;
    }
  } else {
    bf16* op = (bf16*)outv + (((long long)bb * 512) + ibase + pi) * 256 + fb;
    for (int c0 = 0; c0 < 32; c0 += 4) {
      U8 w;
#pragma unroll
      for (int r = 0; r < 4; r++)
        w.h[r] = (bf16)(sh.hs[pi * 264 + fb + c0 + r] * 0.125f);
      *(ushort4*)(op + c0) = w.s;
    }
  }
}

extern "C" void kernel_launch(void* const* d_in, const int* in_sizes, int n_in,
                              void* d_out, int out_size, void* d_ws, size_t ws_size,
                              hipStream_t stream) {
  const float* x    = (const float*)d_in[0];
  const int*   adj  = (const int*)d_in[1];
  const float* W0   = (const float*)d_in[2];
  const float* a1_0 = (const float*)d_in[3];
  const float* a2_0 = (const float*)d_in[4];
  const float* Wo   = (const float*)d_in[5];
  const float* a1_o = (const float*)d_in[6];
  const float* a2_o = (const float*)d_in[7];

  char* p = (char*)d_ws;
  auto take = [&](size_t n) { char* r = p; p += (n + 255) & ~(size_t)255; return r; };
  unsigned long long* maskb = (unsigned long long*)take(32ull * 512 * 8 * 8);
  bf16*  xb   = (bf16*)take(32ull * 512 * 768 * 2);
  bf16*  W0T  = (bf16*)take(8ull * 256 * 768 * 2);
  bf16*  WoT  = (bf16*)take(256ull * 256 * 2);
  bf16*  WhT  = (bf16*)take(8ull * 32 * 256 * 512 * 2);
  float* f1p1 = (float*)take(8ull * 32 * 512 * 4);   // contiguous zero-range start
  float* f2p1 = (float*)take(8ull * 32 * 512 * 4);
  float* f1p2 = (float*)take(32ull * 512 * 4);
  float* f2p2 = (float*)take(32ull * 512 * 4);       // contiguous zero-range end
  float* c1   = (float*)take(8ull * 32 * 512 * 4);
  float* c2   = (float*)take(32ull * 512 * 4);
  bf16* hmid = xb;    // xb dead after layer-1 GEMM; reuse for h_mid
  bf16* Wh2T = WhT;   // WhT dead after pv1; reuse for layer-2

  // zero f1p1..f2p2 (2*524288 + 2*65536 bytes = 73728 float4)
  k_zero<<<288, 256, 0, stream>>>((float4*)f1p1, 73728);
  k_cvt<<<6144, 256, 0, stream>>>(x, xb, 32ll * 512 * 768);
  k_maskpack<<<32768, 256, 0, stream>>>(adj, maskb);
  k_transpose<<<dim3(8, 24, 8), 256, 0, stream>>>(W0, W0T, 768, 256);
  k_transpose<<<dim3(8, 8, 1), 256, 0, stream>>>(Wo, WoT, 256, 256);
  // layer 1
  k_gemm<<<dim3(2, 128, 8), 256, 0, stream>>>(xb, W0T, WhT, 768,
                                              a1_0, a2_0, 256, f1p1, f2p1);
  k_passA<<<dim3(256, 128), 256, 0, stream>>>(f1p1, f2p1, maskb, c1);
  k_pv<8, 0><<<512, 256, 0, stream>>>(WhT, f1p1, c1, f2p1, maskb, hmid);
  // layer 2
  k_gemm<<<dim3(2, 128, 1), 256, 0, stream>>>(hmid, WoT, Wh2T, 256,
                                              a1_o, a2_o, 0, f1p2, f2p2);
  k_passA<<<dim3(32, 128), 256, 0, stream>>>(f1p2, f2p2, maskb, c2);
  k_pv<1, 1><<<512, 256, 0, stream>>>(Wh2T, f1p2, c2, f2p2, maskb, d_out);
}